// Round 7
// baseline (520.417 us; speedup 1.0000x reference)
//
#include <hip/hip_runtime.h>
#include <hip/hip_bf16.h>

#define Bb 4
#define Nn 1024
#define Dd 512
#define Hh 8
#define Ee 5
#define HDd 64

typedef unsigned int u32_t;
typedef unsigned short u16_t;
typedef short s16x8 __attribute__((ext_vector_type(8)));
typedef float f32x4 __attribute__((ext_vector_type(4)));

#define MFMA(a, b, c) __builtin_amdgcn_mfma_f32_16x16x32_bf16((a), (b), (c), 0, 0, 0)

// LDS barrier that does NOT drain vmcnt: lgkm-only fence + raw s_barrier.
__device__ __forceinline__ void lds_barrier() {
    asm volatile("s_waitcnt lgkmcnt(0)" ::: "memory");
    __builtin_amdgcn_s_barrier();
    asm volatile("" ::: "memory");
}

// pack fp32 -> u32: hi16 = truncated top bf16 bits, lo16 = RN bf16 of remainder.
__device__ __forceinline__ u32_t pack32(float x) {
    u32_t u = __float_as_uint(x);
    u32_t hi = u & 0xffff0000u;
    float rem = x - __uint_as_float(hi);
    u32_t r = __float_as_uint(rem);
    u32_t lo = (r + 0x7fffu + ((r >> 16) & 1u)) >> 16;
    return hi | (lo & 0xffffu);
}

// unpack: value ~= hi + lo
__device__ __forceinline__ float unpkf(u32_t x) {
    return __uint_as_float(x & 0xffff0000u) + __uint_as_float(x << 16);
}

// 8 packed u32 (as two uint4) -> hi-frag, lo-frag (bf16x8 as short8)
__device__ __forceinline__ void unpk8(uint4 A, uint4 B, s16x8& h, s16x8& l) {
    union { u16_t u[8]; s16x8 v; } H, L;
    u32_t a[8] = {A.x, A.y, A.z, A.w, B.x, B.y, B.z, B.w};
    #pragma unroll
    for (int i = 0; i < 8; i++) { H.u[i] = (u16_t)(a[i] >> 16); L.u[i] = (u16_t)(a[i] & 0xffffu); }
    h = H.v; l = L.v;
}

// split two packed u32 pairs (4 values) into hi-pair/lo-pair u32 words (2 bf16 each)
__device__ __forceinline__ void split4(uint4 A, uint2& hi, uint2& lo) {
    hi.x = (A.x >> 16) | (A.y & 0xffff0000u);
    hi.y = (A.z >> 16) | (A.w & 0xffff0000u);
    lo.x = (A.x & 0xffffu) | (A.y << 16);
    lo.y = (A.z & 0xffffu) | (A.w << 16);
}

// stage 16 packed elements (4 uint4) -> 2+2 uint4 writes of hi/lo halves (u16 dest)
__device__ __forceinline__ void stage16(uint4 A0, uint4 A1, uint4 A2, uint4 A3,
                                        u16_t* dh, u16_t* dl) {
    uint2 h0, l0, h1, l1, h2, l2, h3, l3;
    split4(A0, h0, l0); split4(A1, h1, l1); split4(A2, h2, l2); split4(A3, h3, l3);
    *(uint4*)(dh + 0) = make_uint4(h0.x, h0.y, h1.x, h1.y);
    *(uint4*)(dh + 8) = make_uint4(h2.x, h2.y, h3.x, h3.y);
    *(uint4*)(dl + 0) = make_uint4(l0.x, l0.y, l1.x, l1.y);
    *(uint4*)(dl + 8) = make_uint4(l2.x, l2.y, l3.x, l3.y);
}

#define HHW(a, b) (((a) >> 16) | ((b) & 0xffff0000u))
#define LLW(a, b) (((a) & 0xffffu) | ((b) << 16))

// ---------- Kernel P: fused mask-normalize (bit-packed) + split-bf16 pack ----------
__global__ __launch_bounds__(256) void pack_prep(const float* __restrict__ x,
                                                 const float* __restrict__ wq,
                                                 const float* __restrict__ wpj,
                                                 const void* __restrict__ msk,
                                                 u32_t* __restrict__ xp,
                                                 u32_t* __restrict__ wqp,
                                                 u32_t* __restrict__ wpp,
                                                 u32_t* __restrict__ mb,
                                                 int* __restrict__ anyB) {
    __shared__ int notint;
    __shared__ int ab[Bb];
    const int tid = threadIdx.x;
    if (blockIdx.x == 1024) {
        if (tid == 0) notint = 0;
        if (tid < Bb) ab[tid] = 0;
        __syncthreads();
        const u32_t* wp = (const u32_t*)msk;
        int bad = 0;
        for (int i = tid; i < 1024; i += 256) bad |= (wp[i] > 1u);
        if (bad) atomicOr(&notint, 1);
        __syncthreads();
        const int isbyte = notint;
        const unsigned char* bp = (const unsigned char*)msk;
        if (tid < 128) {
            u32_t wbits = 0;
            for (int k = 0; k < 32; k++) {
                const int i = tid * 32 + k;
                const int v = isbyte ? (bp[i] != 0) : (wp[i] != 0);
                wbits |= (u32_t)v << k;
            }
            mb[tid] = wbits;
            if (wbits) atomicOr(&ab[tid >> 5], 1);
        }
        __syncthreads();
        if (tid < Bb) anyB[tid] = ab[tid];
        return;
    }
    const int gt = blockIdx.x * 256 + tid;
    const int gs = 1024 * 256;
    const float4* xs = (const float4*)x;
    uint4* xd = (uint4*)xp;
    for (int i = gt; i < (Bb * Nn * Dd) / 4; i += gs) {
        float4 v = xs[i];
        xd[i] = make_uint4(pack32(v.x), pack32(v.y), pack32(v.z), pack32(v.w));
    }
    const float4* qs = (const float4*)wq;
    uint4* qd = (uint4*)wqp;
    for (int i = gt; i < (3 * Dd * Dd) / 4; i += gs) {
        float4 v = qs[i];
        qd[i] = make_uint4(pack32(v.x), pack32(v.y), pack32(v.z), pack32(v.w));
    }
    const float4* ps = (const float4*)wpj;
    uint4* pd = (uint4*)wpp;
    for (int i = gt; i < (Dd * Dd) / 4; i += gs) {
        float4 v = ps[i];
        pd[i] = make_uint4(pack32(v.x), pack32(v.y), pack32(v.z), pack32(v.w));
    }
}

// ---------- Kernel A: qkv = x @ w_qkv^T; reg-prefetch + lgkm-only barriers ----------
__global__ __launch_bounds__(256) void qkv_mfma(const u32_t* __restrict__ xp,
                                                const u32_t* __restrict__ wp,
                                                u32_t* __restrict__ q32,
                                                u32_t* __restrict__ k32,
                                                u32_t* __restrict__ v32) {
    __shared__ __align__(16) u16_t Xh[64 * 72], Xl[64 * 72];
    __shared__ __align__(16) u16_t Wh[64 * 72], Wl[64 * 72];
    const int tid = threadIdx.x;
    const int wv = tid >> 6, lane = tid & 63, lm = lane & 15, quad = lane >> 4;
    const int m0 = blockIdx.y * 64, c0 = blockIdx.x * 64;
    const int row = tid >> 2, dq = tid & 3;
    const uint4* x4 = (const uint4*)xp;
    const uint4* w4 = (const uint4*)wp;

    const size_t xb0 = (size_t)(m0 + row) * 128 + dq * 4;
    const size_t wb0 = (size_t)(c0 + row) * 128 + dq * 4;
    uint4 xa0 = x4[xb0 + 0], xa1 = x4[xb0 + 1], xa2 = x4[xb0 + 2], xa3 = x4[xb0 + 3];
    uint4 wa0 = w4[wb0 + 0], wa1 = w4[wb0 + 1], wa2 = w4[wb0 + 2], wa3 = w4[wb0 + 3];

    f32x4 acc[4];
    #pragma unroll
    for (int nt = 0; nt < 4; nt++) acc[nt] = {0.f, 0.f, 0.f, 0.f};

    for (int kt = 0; kt < 8; kt++) {
        lds_barrier();
        stage16(xa0, xa1, xa2, xa3, &Xh[row * 72 + dq * 16], &Xl[row * 72 + dq * 16]);
        stage16(wa0, wa1, wa2, wa3, &Wh[row * 72 + dq * 16], &Wl[row * 72 + dq * 16]);
        const int ktn = (kt < 7) ? kt + 1 : 7;
        xa0 = x4[xb0 + ktn * 16 + 0]; xa1 = x4[xb0 + ktn * 16 + 1];
        xa2 = x4[xb0 + ktn * 16 + 2]; xa3 = x4[xb0 + ktn * 16 + 3];
        wa0 = w4[wb0 + ktn * 16 + 0]; wa1 = w4[wb0 + ktn * 16 + 1];
        wa2 = w4[wb0 + ktn * 16 + 2]; wa3 = w4[wb0 + ktn * 16 + 3];
        lds_barrier();
        s16x8 ah[2], al[2];
        #pragma unroll
        for (int ks = 0; ks < 2; ks++) {
            ah[ks] = *(const s16x8*)&Xh[(16 * wv + lm) * 72 + ks * 32 + quad * 8];
            al[ks] = *(const s16x8*)&Xl[(16 * wv + lm) * 72 + ks * 32 + quad * 8];
        }
        #pragma unroll
        for (int nt = 0; nt < 4; nt++) {
            #pragma unroll
            for (int ks = 0; ks < 2; ks++) {
                s16x8 bh = *(const s16x8*)&Wh[(16 * nt + lm) * 72 + ks * 32 + quad * 8];
                s16x8 bl = *(const s16x8*)&Wl[(16 * nt + lm) * 72 + ks * 32 + quad * 8];
                acc[nt] = MFMA(ah[ks], bh, acc[nt]);
                acc[nt] = MFMA(ah[ks], bl, acc[nt]);
                acc[nt] = MFMA(al[ks], bh, acc[nt]);
            }
        }
    }
    #pragma unroll
    for (int nt = 0; nt < 4; nt++) {
        const int c = c0 + 16 * nt + lm;
        const int s = c >> 9, hd = c & 511, h = hd >> 6, d = hd & 63;
        u32_t* dst = (s == 0) ? q32 : (s == 1) ? k32 : v32;
        #pragma unroll
        for (int r = 0; r < 4; r++) {
            const int m = m0 + 16 * wv + 4 * quad + r;
            const int b = m >> 10, n = m & (Nn - 1);
            dst[(((size_t)b * Hh + h) * Nn + n) * HDd + d] = pack32(acc[nt][r]);
        }
    }
}

// ---------- Kernel B: flash attention, j-split, K/VT TIME-SHARED LDS buffer ----------
// 4 barrier phases/iter: A) stage K  B) QK^T reads K  C) stage VT over K (softmax
// VALU phase hides the ds_writes)  D) PV reads VT. LDS = KV 18432 + P 17408 =
// 35840 B -> 4 blocks/CU robustly; grid 1024 = exactly 4/CU, 4 waves/SIMD.
__global__ __launch_bounds__(256, 4) void attn_mfma(const u32_t* __restrict__ q32,
                                                    const u32_t* __restrict__ k32,
                                                    const u32_t* __restrict__ v32,
                                                    const float* __restrict__ ef,
                                                    const u32_t* __restrict__ mb,
                                                    const int* __restrict__ anyB,
                                                    const float* __restrict__ wep,
                                                    const float* __restrict__ weg,
                                                    const float* __restrict__ beg,
                                                    u32_t* __restrict__ pout0,
                                                    u32_t* __restrict__ pout1,
                                                    float2* __restrict__ ml0,
                                                    float2* __restrict__ ml1) {
    // LDS: KV (K during QK^T, VT during PV) 18432 + P 17408 = 35840 B
    __shared__ __align__(16) u16_t KVh[64 * 72], KVl[64 * 72];
    __shared__ __align__(16) u32_t Ppk[64 * 68];

    const int tid = threadIdx.x;
    const int wv = tid >> 6, lane = tid & 63, lm = lane & 15, quad = lane >> 4;
    const int i0 = (blockIdx.x & 15) * 64;
    const int half = blockIdx.x >> 4;
    const int jbase = half * 512;
    const int h  = blockIdx.y;
    const int b  = blockIdx.z;
    const int row = tid >> 2, dq = tid & 3;     // K staging map
    const int jo = tid >> 5, dch = tid & 31;    // V staging map
    const int wsw = 8 * ((dch >> 2) & 1);       // VT write swizzle ((d>>3)&1 for d=2dch)
    const int vsw = 8 * ((lm >> 3) & 1);        // VT read swizzle

    const uint4* kg4 = (const uint4*)(k32 + (((size_t)b * Hh + h) * Nn) * HDd);
    const uint2* vg2 = (const uint2*)(v32 + (((size_t)b * Hh + h) * Nn) * HDd);
    const u32_t* mbB = mb + b * 32;

    const int i_sm = i0 + 16 * wv + lm;          // this lane's softmax row

    // ---- prologue: issue Q-frag, K, V, ef, mask loads for first tile ----
    const u32_t* qrow = q32 + (((size_t)b * Hh + h) * Nn + i_sm) * HDd;
    uint4 qA0 = *(const uint4*)&qrow[quad * 8];
    uint4 qB0 = *(const uint4*)&qrow[quad * 8 + 4];
    uint4 qA1 = *(const uint4*)&qrow[32 + quad * 8];
    uint4 qB1 = *(const uint4*)&qrow[32 + quad * 8 + 4];
    const size_t kb0 = (size_t)(jbase + row) * 16 + dq * 4;
    uint4 kr0 = kg4[kb0 + 0], kr1 = kg4[kb0 + 1], kr2 = kg4[kb0 + 2], kr3 = kg4[kb0 + 3];
    uint2 vq0 = vg2[(jbase + 8 * jo + 0) * 32 + dch], vq1 = vg2[(jbase + 8 * jo + 1) * 32 + dch],
          vq2 = vg2[(jbase + 8 * jo + 2) * 32 + dch], vq3 = vg2[(jbase + 8 * jo + 3) * 32 + dch],
          vq4 = vg2[(jbase + 8 * jo + 4) * 32 + dch], vq5 = vg2[(jbase + 8 * jo + 5) * 32 + dch],
          vq6 = vg2[(jbase + 8 * jo + 6) * 32 + dch], vq7 = vg2[(jbase + 8 * jo + 7) * 32 + dch];

    const float* efL = ef + ((size_t)(b * Nn + i_sm) * Nn + 4 * quad) * Ee;
    uint2 mwc = *(const uint2*)&mbB[jbase >> 5];
    float4 er4[4][5];
    #pragma unroll
    for (int jn = 0; jn < 4; jn++) {
        const float4* p4 = (const float4*)(efL + (size_t)(jbase + 16 * jn) * Ee);
        #pragma unroll
        for (int c = 0; c < 5; c++) er4[jn][c] = p4[c];
    }

    const float wp0 = wep[h*Ee+0], wp1 = wep[h*Ee+1], wp2 = wep[h*Ee+2],
                wp3 = wep[h*Ee+3], wp4 = wep[h*Ee+4];
    const float wg0 = weg[h*Ee+0], wg1 = weg[h*Ee+1], wg2 = weg[h*Ee+2],
                wg3 = weg[h*Ee+3], wg4 = weg[h*Ee+4];
    const float bgs = beg[h];
    const int anyb = anyB[b];
    const int rvs = anyb && ((mbB[i_sm >> 5] >> (i_sm & 31)) & 1);

    // ---- Q fragments in registers ----
    s16x8 qh[2], ql[2];
    unpk8(qA0, qB0, qh[0], ql[0]);
    unpk8(qA1, qB1, qh[1], ql[1]);

    float m_ = -1e30f, l_ = 0.f;
    f32x4 accO[4];
    #pragma unroll
    for (int dn = 0; dn < 4; dn++) accO[dn] = {0.f, 0.f, 0.f, 0.f};
    const int xk = 8 * (lm & 3);                 // P column XOR-swizzle key

    for (int jt = 0; jt < 8; jt++) {
        const int j0n = jbase + ((jt < 7) ? jt + 1 : 7) * 64;

        lds_barrier();   // A: all waves' PV reads of prev VT done

        // ---- stage K from regs: [j][d] split ----
        stage16(kr0, kr1, kr2, kr3, &KVh[row * 72 + dq * 16], &KVl[row * 72 + dq * 16]);
        // ---- issue next-tile K loads (in flight across B + QK^T) ----
        {
            const size_t kbn = (size_t)(j0n + row) * 16 + dq * 4;
            kr0 = kg4[kbn + 0]; kr1 = kg4[kbn + 1]; kr2 = kg4[kbn + 2]; kr3 = kg4[kbn + 3];
        }

        lds_barrier();   // B: K visible

        // ---- QK^T swapped: Sp[jn][r] = S[jloc = 16jn+4quad+r][i = i_sm] ----
        f32x4 Sp[4];
        #pragma unroll
        for (int jn = 0; jn < 4; jn++) {
            f32x4 s = {0.f, 0.f, 0.f, 0.f};
            #pragma unroll
            for (int ks = 0; ks < 2; ks++) {
                s16x8 kh = *(const s16x8*)&KVh[(16 * jn + lm) * 72 + ks * 32 + quad * 8];
                s16x8 kl = *(const s16x8*)&KVl[(16 * jn + lm) * 72 + ks * 32 + quad * 8];
                s = MFMA(kh, qh[ks], s);
                s = MFMA(kh, ql[ks], s);
                s = MFMA(kl, qh[ks], s);
            }
            Sp[jn] = s;
        }

        lds_barrier();   // C: all waves' K reads done; safe to overwrite with VT

        // ---- stage VT over K: rows d0=2dch, d1=d0+1; swizzled j-col ----
        {
            const int d0 = 2 * dch, d1 = d0 + 1;
            const int jcol = (8 * jo) ^ wsw;
            uint4 H0 = make_uint4(HHW(vq0.x, vq1.x), HHW(vq2.x, vq3.x),
                                  HHW(vq4.x, vq5.x), HHW(vq6.x, vq7.x));
            uint4 L0 = make_uint4(LLW(vq0.x, vq1.x), LLW(vq2.x, vq3.x),
                                  LLW(vq4.x, vq5.x), LLW(vq6.x, vq7.x));
            uint4 H1 = make_uint4(HHW(vq0.y, vq1.y), HHW(vq2.y, vq3.y),
                                  HHW(vq4.y, vq5.y), HHW(vq6.y, vq7.y));
            uint4 L1 = make_uint4(LLW(vq0.y, vq1.y), LLW(vq2.y, vq3.y),
                                  LLW(vq4.y, vq5.y), LLW(vq6.y, vq7.y));
            *(uint4*)&KVh[d0 * 72 + jcol] = H0;
            *(uint4*)&KVl[d0 * 72 + jcol] = L0;
            *(uint4*)&KVh[d1 * 72 + jcol] = H1;
            *(uint4*)&KVl[d1 * 72 + jcol] = L1;
        }
        // ---- issue next-tile V loads ----
        {
            vq0 = vg2[(j0n + 8 * jo + 0) * 32 + dch];
            vq1 = vg2[(j0n + 8 * jo + 1) * 32 + dch];
            vq2 = vg2[(j0n + 8 * jo + 2) * 32 + dch];
            vq3 = vg2[(j0n + 8 * jo + 3) * 32 + dch];
            vq4 = vg2[(j0n + 8 * jo + 4) * 32 + dch];
            vq5 = vg2[(j0n + 8 * jo + 5) * 32 + dch];
            vq6 = vg2[(j0n + 8 * jo + 6) * 32 + dch];
            vq7 = vg2[(j0n + 8 * jo + 7) * 32 + dch];
        }

        // ---- gate/bias/mask + softmax VALU phase (hides VT ds_writes + loads) ----
        const u32_t sj[4] = {mwc.x >> (4 * quad), mwc.x >> (4 * quad + 16),
                             mwc.y >> (4 * quad), mwc.y >> (4 * quad + 16)};
        float pp[4][4];
        #pragma unroll
        for (int jn = 0; jn < 4; jn++) {
            #pragma unroll
            for (int r = 0; r < 4; r++) {
                const int mjv = (sj[jn] >> r) & 1;
                const int f = r * 5;
                const float e0 = er4[jn][(f+0)>>2][(f+0)&3];
                const float e1 = er4[jn][(f+1)>>2][(f+1)&3];
                const float e2 = er4[jn][(f+2)>>2][(f+2)&3];
                const float e3 = er4[jn][(f+3)>>2][(f+3)&3];
                const float e4 = er4[jn][(f+4)>>2][(f+4)&3];
                const float bias = fmaf(e0, wp0, fmaf(e1, wp1, fmaf(e2, wp2, fmaf(e3, wp3, e4 * wp4))));
                const float gv = fmaf(e0, wg0, fmaf(e1, wg1, fmaf(e2, wg2, fmaf(e3, wg3, fmaf(e4, wg4, bgs)))));
                const float gate = __builtin_amdgcn_rcpf(1.f + __expf(-gv));
                const float val = fmaf(Sp[jn][r], 0.125f, gate * bias);
                pp[jn][r] = rvs ? (mjv ? val : -1e30f) : 0.f;
            }
        }
        // ---- reload ef/mask for next tile ----
        mwc = *(const uint2*)&mbB[j0n >> 5];
        #pragma unroll
        for (int jn = 0; jn < 4; jn++) {
            const float4* p4 = (const float4*)(efL + (size_t)(j0n + 16 * jn) * Ee);
            #pragma unroll
            for (int c = 0; c < 5; c++) er4[jn][c] = p4[c];
        }

        // ---- lane-local online softmax ----
        float tmax = fmaxf(fmaxf(fmaxf(pp[0][0], pp[0][1]), fmaxf(pp[0][2], pp[0][3])),
                           fmaxf(fmaxf(pp[1][0], pp[1][1]), fmaxf(pp[1][2], pp[1][3])));
        tmax = fmaxf(tmax,
               fmaxf(fmaxf(fmaxf(pp[2][0], pp[2][1]), fmaxf(pp[2][2], pp[2][3])),
                     fmaxf(fmaxf(pp[3][0], pp[3][1]), fmaxf(pp[3][2], pp[3][3]))));
        tmax = fmaxf(tmax, __shfl_xor(tmax, 16));
        tmax = fmaxf(tmax, __shfl_xor(tmax, 32));
        const float mnew = fmaxf(m_, tmax);
        const float alpha = __expf(m_ - mnew);
        float ps = 0.f;
        #pragma unroll
        for (int jn = 0; jn < 4; jn++)
            #pragma unroll
            for (int r = 0; r < 4; r++) { pp[jn][r] = __expf(pp[jn][r] - mnew); ps += pp[jn][r]; }
        ps += __shfl_xor(ps, 16);
        ps += __shfl_xor(ps, 32);
        m_ = mnew;
        l_ = l_ * alpha + ps;
        float a4[4];
        #pragma unroll
        for (int r = 0; r < 4; r++) a4[r] = __shfl(alpha, 4 * quad + r);
        #pragma unroll
        for (int dn = 0; dn < 4; dn++)
            #pragma unroll
            for (int r = 0; r < 4; r++) accO[dn][r] *= a4[r];

        // ---- P write: own row, XOR-swizzled cols (wave-private rows) ----
        #pragma unroll
        for (int jn = 0; jn < 4; jn++) {
            #pragma unroll
            for (int p = 0; p < 2; p++) {
                const int col = (16 * jn + 4 * quad + 2 * p) ^ xk;
                *(uint2*)&Ppk[(16 * wv + lm) * 68 + col] =
                    make_uint2(pack32(pp[jn][2 * p]), pack32(pp[jn][2 * p + 1]));
            }
        }

        lds_barrier();   // D: VT visible to all waves

        // ---- PV: reads VT (shared buffer) + own P rows ----
        s16x8 ph[2], pl[2];
        #pragma unroll
        for (int ks2 = 0; ks2 < 2; ks2++) {
            const int off = (16 * wv + lm) * 68 + ((ks2 * 32 + quad * 8) ^ xk);
            uint4 A = *(const uint4*)&Ppk[off];
            uint4 B2 = *(const uint4*)&Ppk[off + 4];
            unpk8(A, B2, ph[ks2], pl[ks2]);
        }
        #pragma unroll
        for (int dn = 0; dn < 4; dn++) {
            f32x4 c = accO[dn];
            #pragma unroll
            for (int ks2 = 0; ks2 < 2; ks2++) {
                const int off = (16 * dn + lm) * 72 + ((ks2 * 32 + quad * 8) ^ vsw);
                s16x8 vh = *(const s16x8*)&KVh[off];
                s16x8 vl = *(const s16x8*)&KVl[off];
                c = MFMA(ph[ks2], vh, c);
                c = MFMA(ph[ks2], vl, c);
                c = MFMA(pl[ks2], vh, c);
            }
            accO[dn] = c;
        }
    }

    // ---- epilogue: raw partials (no normalization; combine kernel merges) ----
    u32_t* pout = half ? pout1 : pout0;
    float2* mlo = half ? ml1 : ml0;
    #pragma unroll
    for (int r = 0; r < 4; r++) {
        const int i = i0 + 16 * wv + 4 * quad + r;
        #pragma unroll
        for (int dn = 0; dn < 4; dn++)
            pout[(size_t)(b * Nn + i) * Dd + h * HDd + 16 * dn + lm] = pack32(accO[dn][r]);
    }
    if (quad == 0) mlo[((size_t)b * Hh + h) * Nn + i_sm] = make_float2(m_, l_);
}

// ---------- Kernel M: merge the two j-half partials -> packed aout ----------
__global__ __launch_bounds__(256) void combine(const u32_t* __restrict__ p0,
                                               const u32_t* __restrict__ p1,
                                               const float2* __restrict__ mla,
                                               const float2* __restrict__ mlb,
                                               u32_t* __restrict__ aop) {
    const int g = blockIdx.x * 256 + threadIdx.x;    // 524288 total = 32768 rows x 16
    const int rowi = g >> 4, dq = (g & 15) * 4;
    const int b = rowi >> 13, h = (rowi >> 10) & 7, i = rowi & 1023;
    const float2 A = mla[rowi], B = mlb[rowi];
    const float mN = fmaxf(A.x, B.x);
    const float a0 = __expf(A.x - mN), a1 = __expf(B.x - mN);
    const float linv = __builtin_amdgcn_rcpf(fmaf(A.y, a0, B.y * a1));
    const size_t base = ((size_t)(b * Nn + i)) * Dd + h * HDd + dq;
    const uint4 u0 = *(const uint4*)&p0[base];
    const uint4 u1 = *(const uint4*)&p1[base];
    uint4 o;
    o.x = pack32((unpkf(u0.x) * a0 + unpkf(u1.x) * a1) * linv);
    o.y = pack32((unpkf(u0.y) * a0 + unpkf(u1.y) * a1) * linv);
    o.z = pack32((unpkf(u0.z) * a0 + unpkf(u1.z) * a1) * linv);
    o.w = pack32((unpkf(u0.w) * a0 + unpkf(u1.w) * a1) * linv);
    *(uint4*)&aop[base] = o;
}

// ---------- Kernel C: out = aout @ w_proj^T + bias; reg-prefetch + lgkm barriers ----------
__global__ __launch_bounds__(256) void out_mfma(const u32_t* __restrict__ ap,
                                                const u32_t* __restrict__ wp,
                                                const float* __restrict__ bias,
                                                float* __restrict__ out) {
    __shared__ __align__(16) u16_t Xh[64 * 72], Xl[64 * 72];
    __shared__ __align__(16) u16_t Wh[64 * 72], Wl[64 * 72];
    const int tid = threadIdx.x;
    const int wv = tid >> 6, lane = tid & 63, lm = lane & 15, quad = lane >> 4;
    const int m0 = blockIdx.y * 64, c0 = blockIdx.x * 64;
    const int row = tid >> 2, dq = tid & 3;
    const uint4* a4 = (const uint4*)ap;
    const uint4* w4 = (const uint4*)wp;

    const size_t ab0 = (size_t)(m0 + row) * 128 + dq * 4;
    const size_t wb0 = (size_t)(c0 + row) * 128 + dq * 4;
    uint4 xa0 = a4[ab0 + 0], xa1 = a4[ab0 + 1], xa2 = a4[ab0 + 2], xa3 = a4[ab0 + 3];
    uint4 wa0 = w4[wb0 + 0], wa1 = w4[wb0 + 1], wa2 = w4[wb0 + 2], wa3 = w4[wb0 + 3];

    f32x4 acc[4];
    #pragma unroll
    for (int nt = 0; nt < 4; nt++) acc[nt] = {0.f, 0.f, 0.f, 0.f};

    for (int kt = 0; kt < 8; kt++) {
        lds_barrier();
        stage16(xa0, xa1, xa2, xa3, &Xh[row * 72 + dq * 16], &Xl[row * 72 + dq * 16]);
        stage16(wa0, wa1, wa2, wa3, &Wh[row * 72 + dq * 16], &Wl[row * 72 + dq * 16]);
        const int ktn = (kt < 7) ? kt + 1 : 7;
        xa0 = a4[ab0 + ktn * 16 + 0]; xa1 = a4[ab0 + ktn * 16 + 1];
        xa2 = a4[ab0 + ktn * 16 + 2]; xa3 = a4[ab0 + ktn * 16 + 3];
        wa0 = w4[wb0 + ktn * 16 + 0]; wa1 = w4[wb0 + ktn * 16 + 1];
        wa2 = w4[wb0 + ktn * 16 + 2]; wa3 = w4[wb0 + ktn * 16 + 3];
        lds_barrier();
        s16x8 ah[2], al[2];
        #pragma unroll
        for (int ks = 0; ks < 2; ks++) {
            ah[ks] = *(const s16x8*)&Xh[(16 * wv + lm) * 72 + ks * 32 + quad * 8];
            al[ks] = *(const s16x8*)&Xl[(16 * wv + lm) * 72 + ks * 32 + quad * 8];
        }
        #pragma unroll
        for (int nt = 0; nt < 4; nt++) {
            #pragma unroll
            for (int ks = 0; ks < 2; ks++) {
                s16x8 bh = *(const s16x8*)&Wh[(16 * nt + lm) * 72 + ks * 32 + quad * 8];
                s16x8 bl = *(const s16x8*)&Wl[(16 * nt + lm) * 72 + ks * 32 + quad * 8];
                acc[nt] = MFMA(ah[ks], bh, acc[nt]);
                acc[nt] = MFMA(ah[ks], bl, acc[nt]);
                acc[nt] = MFMA(al[ks], bh, acc[nt]);
            }
        }
    }
    #pragma unroll
    for (int nt = 0; nt < 4; nt++) {
        const int c = c0 + 16 * nt + lm;
        const float bc = bias[c];
        #pragma unroll
        for (int r = 0; r < 4; r++) {
            const int m = m0 + 16 * wv + 4 * quad + r;
            out[(size_t)m * Dd + c] = acc[nt][r] + bc;
        }
    }
}

extern "C" void kernel_launch(void* const* d_in, const int* in_sizes, int n_in,
                              void* d_out, int out_size, void* d_ws, size_t ws_size,
                              hipStream_t stream) {
    const float* x    = (const float*)d_in[0];
    const float* ef   = (const float*)d_in[1];
    const void*  msk  = d_in[2];
    const float* wqkv = (const float*)d_in[3];
    const float* wep  = (const float*)d_in[4];
    const float* weg  = (const float*)d_in[5];
    const float* beg  = (const float*)d_in[6];
    const float* wpj  = (const float*)d_in[7];
    const float* bpj  = (const float*)d_in[8];
    float* out = (float*)d_out;

    u32_t* mbits = (u32_t*)d_ws;                  // 128 u32 bit-packed mask
    int* anyB = (int*)(mbits + 128);              // 16 ints
    u32_t* q32 = (u32_t*)(anyB + 16);
    const size_t per = (size_t)Bb * Hh * Nn * HDd;   // 2,097,152
    u32_t* k32 = q32 + per;
    u32_t* v32 = k32 + per;
    u32_t* aop = v32 + per;                       // B*N*D packed u32
    u32_t* xp  = aop + (size_t)Bb * Nn * Dd;      // B*N*D packed u32 (reused as pout0)
    u32_t* wqp = xp + (size_t)Bb * Nn * Dd;       // 3*D*D packed u32
    u32_t* wpp = wqp + (size_t)3 * Dd * Dd;       // D*D packed u32
    u32_t* pout1 = wpp + (size_t)Dd * Dd;         // B*N*D packed u32
    float2* ml0 = (float2*)(pout1 + (size_t)Bb * Nn * Dd);   // B*H*N float2
    float2* ml1 = ml0 + (size_t)Bb * Hh * Nn;
    u32_t* pout0 = xp;                            // xp is dead after qkv_mfma

    pack_prep<<<1025, 256, 0, stream>>>(x, wqkv, wpj, msk, xp, wqp, wpp, mbits, anyB);
    qkv_mfma<<<dim3(24, 64), 256, 0, stream>>>(xp, wqp, q32, k32, v32);
    attn_mfma<<<dim3(32, Hh, Bb), 256, 0, stream>>>(q32, k32, v32, ef, mbits, anyB,
                                                    wep, weg, beg, pout0, pout1, ml0, ml1);
    combine<<<2048, 256, 0, stream>>>(pout0, pout1, ml0, ml1, aop);
    out_mfma<<<dim3(8, 64), 256, 0, stream>>>(aop, wpp, bpj, out);
}

// Round 8
// 295.843 us; speedup vs baseline: 1.7591x; 1.7591x over previous
//
#include <hip/hip_runtime.h>
#include <hip/hip_bf16.h>

#define Bb 4
#define Nn 1024
#define Dd 512
#define Hh 8
#define Ee 5
#define HDd 64

typedef unsigned int u32_t;
typedef unsigned short u16_t;
typedef short s16x8 __attribute__((ext_vector_type(8)));
typedef float f32x4 __attribute__((ext_vector_type(4)));

#define MFMA(a, b, c) __builtin_amdgcn_mfma_f32_16x16x32_bf16((a), (b), (c), 0, 0, 0)

// LDS barrier that does NOT drain vmcnt: lgkm-only fence + raw s_barrier.
__device__ __forceinline__ void lds_barrier() {
    asm volatile("s_waitcnt lgkmcnt(0)" ::: "memory");
    __builtin_amdgcn_s_barrier();
    asm volatile("" ::: "memory");
}

// pack fp32 -> u32: hi16 = truncated top bf16 bits, lo16 = RN bf16 of remainder.
__device__ __forceinline__ u32_t pack32(float x) {
    u32_t u = __float_as_uint(x);
    u32_t hi = u & 0xffff0000u;
    float rem = x - __uint_as_float(hi);
    u32_t r = __float_as_uint(rem);
    u32_t lo = (r + 0x7fffu + ((r >> 16) & 1u)) >> 16;
    return hi | (lo & 0xffffu);
}

// 8 packed u32 (as two uint4) -> hi-frag, lo-frag (bf16x8 as short8)
__device__ __forceinline__ void unpk8(uint4 A, uint4 B, s16x8& h, s16x8& l) {
    union { u16_t u[8]; s16x8 v; } H, L;
    u32_t a[8] = {A.x, A.y, A.z, A.w, B.x, B.y, B.z, B.w};
    #pragma unroll
    for (int i = 0; i < 8; i++) { H.u[i] = (u16_t)(a[i] >> 16); L.u[i] = (u16_t)(a[i] & 0xffffu); }
    h = H.v; l = L.v;
}

// split two packed u32 pairs (4 values) into hi-pair/lo-pair u32 words (2 bf16 each)
__device__ __forceinline__ void split4(uint4 A, uint2& hi, uint2& lo) {
    hi.x = (A.x >> 16) | (A.y & 0xffff0000u);
    hi.y = (A.z >> 16) | (A.w & 0xffff0000u);
    lo.x = (A.x & 0xffffu) | (A.y << 16);
    lo.y = (A.z & 0xffffu) | (A.w << 16);
}

// stage 16 packed elements (4 uint4) -> 2+2 uint4 writes of hi/lo halves (u16 dest)
__device__ __forceinline__ void stage16(uint4 A0, uint4 A1, uint4 A2, uint4 A3,
                                        u16_t* dh, u16_t* dl) {
    uint2 h0, l0, h1, l1, h2, l2, h3, l3;
    split4(A0, h0, l0); split4(A1, h1, l1); split4(A2, h2, l2); split4(A3, h3, l3);
    *(uint4*)(dh + 0) = make_uint4(h0.x, h0.y, h1.x, h1.y);
    *(uint4*)(dh + 8) = make_uint4(h2.x, h2.y, h3.x, h3.y);
    *(uint4*)(dl + 0) = make_uint4(l0.x, l0.y, l1.x, l1.y);
    *(uint4*)(dl + 8) = make_uint4(l2.x, l2.y, l3.x, l3.y);
}

// stage 8 packed elements (2 uint4) -> 1+1 uint4 writes of hi/lo halves
__device__ __forceinline__ void stage8(uint4 A0, uint4 A1, u16_t* dh, u16_t* dl) {
    uint2 h0, l0, h1, l1;
    split4(A0, h0, l0); split4(A1, h1, l1);
    *(uint4*)dh = make_uint4(h0.x, h0.y, h1.x, h1.y);
    *(uint4*)dl = make_uint4(l0.x, l0.y, l1.x, l1.y);
}

#define HHW(a, b) (((a) >> 16) | ((b) & 0xffff0000u))
#define LLW(a, b) (((a) & 0xffffu) | ((b) << 16))

// ---------- Kernel P: fused mask-normalize (bit-packed) + split-bf16 pack ----------
__global__ __launch_bounds__(256) void pack_prep(const float* __restrict__ x,
                                                 const float* __restrict__ wq,
                                                 const float* __restrict__ wpj,
                                                 const void* __restrict__ msk,
                                                 u32_t* __restrict__ xp,
                                                 u32_t* __restrict__ wqp,
                                                 u32_t* __restrict__ wpp,
                                                 u32_t* __restrict__ mb,
                                                 int* __restrict__ anyB) {
    __shared__ int notint;
    __shared__ int ab[Bb];
    const int tid = threadIdx.x;
    if (blockIdx.x == 1024) {
        if (tid == 0) notint = 0;
        if (tid < Bb) ab[tid] = 0;
        __syncthreads();
        const u32_t* wp = (const u32_t*)msk;
        int bad = 0;
        for (int i = tid; i < 1024; i += 256) bad |= (wp[i] > 1u);
        if (bad) atomicOr(&notint, 1);
        __syncthreads();
        const int isbyte = notint;
        const unsigned char* bp = (const unsigned char*)msk;
        if (tid < 128) {
            u32_t wbits = 0;
            for (int k = 0; k < 32; k++) {
                const int i = tid * 32 + k;
                const int v = isbyte ? (bp[i] != 0) : (wp[i] != 0);
                wbits |= (u32_t)v << k;
            }
            mb[tid] = wbits;
            if (wbits) atomicOr(&ab[tid >> 5], 1);
        }
        __syncthreads();
        if (tid < Bb) anyB[tid] = ab[tid];
        return;
    }
    const int gt = blockIdx.x * 256 + tid;
    const int gs = 1024 * 256;
    const float4* xs = (const float4*)x;
    uint4* xd = (uint4*)xp;
    for (int i = gt; i < (Bb * Nn * Dd) / 4; i += gs) {
        float4 v = xs[i];
        xd[i] = make_uint4(pack32(v.x), pack32(v.y), pack32(v.z), pack32(v.w));
    }
    const float4* qs = (const float4*)wq;
    uint4* qd = (uint4*)wqp;
    for (int i = gt; i < (3 * Dd * Dd) / 4; i += gs) {
        float4 v = qs[i];
        qd[i] = make_uint4(pack32(v.x), pack32(v.y), pack32(v.z), pack32(v.w));
    }
    const float4* ps = (const float4*)wpj;
    uint4* pd = (uint4*)wpp;
    for (int i = gt; i < (Dd * Dd) / 4; i += gs) {
        float4 v = ps[i];
        pd[i] = make_uint4(pack32(v.x), pack32(v.y), pack32(v.z), pack32(v.w));
    }
}

// ---------- Kernel A: qkv = x @ w_qkv^T; 512 threads, M-tile 128, N-tile 64 ----------
// 8 waves: wave wv owns rows 16wv..16wv+15 of the 128-row X tile; W tile shared.
// LDS = X 36864 + W 18432 = 55296 B -> 2 blocks/CU -> 16 waves/CU (4/SIMD, 2x prev).
__global__ __launch_bounds__(512) void qkv_mfma(const u32_t* __restrict__ xp,
                                                const u32_t* __restrict__ wp,
                                                u32_t* __restrict__ q32,
                                                u32_t* __restrict__ k32,
                                                u32_t* __restrict__ v32) {
    __shared__ __align__(16) u16_t Xh[128 * 72], Xl[128 * 72];
    __shared__ __align__(16) u16_t Wh[64 * 72], Wl[64 * 72];
    const int tid = threadIdx.x;
    const int wv = tid >> 6, lane = tid & 63, lm = lane & 15, quad = lane >> 4;
    const int m0 = blockIdx.y * 128, c0 = blockIdx.x * 64;
    const int xrow = tid >> 2, xdq = tid & 3;    // X staging: 128 rows, 4 thr/row
    const int wrow = tid >> 3, wdq = tid & 7;    // W staging: 64 rows, 8 thr/row
    const uint4* x4 = (const uint4*)xp;
    const uint4* w4 = (const uint4*)wp;

    const size_t xb0 = (size_t)(m0 + xrow) * 128 + xdq * 4;
    const size_t wb0 = (size_t)(c0 + wrow) * 128 + wdq * 2;
    uint4 xa0 = x4[xb0 + 0], xa1 = x4[xb0 + 1], xa2 = x4[xb0 + 2], xa3 = x4[xb0 + 3];
    uint4 wa0 = w4[wb0 + 0], wa1 = w4[wb0 + 1];

    f32x4 acc[4];
    #pragma unroll
    for (int nt = 0; nt < 4; nt++) acc[nt] = {0.f, 0.f, 0.f, 0.f};

    for (int kt = 0; kt < 8; kt++) {
        lds_barrier();
        stage16(xa0, xa1, xa2, xa3, &Xh[xrow * 72 + xdq * 16], &Xl[xrow * 72 + xdq * 16]);
        stage8(wa0, wa1, &Wh[wrow * 72 + wdq * 8], &Wl[wrow * 72 + wdq * 8]);
        const int ktn = (kt < 7) ? kt + 1 : 7;
        xa0 = x4[xb0 + ktn * 16 + 0]; xa1 = x4[xb0 + ktn * 16 + 1];
        xa2 = x4[xb0 + ktn * 16 + 2]; xa3 = x4[xb0 + ktn * 16 + 3];
        wa0 = w4[wb0 + ktn * 16 + 0]; wa1 = w4[wb0 + ktn * 16 + 1];
        lds_barrier();
        s16x8 ah[2], al[2];
        #pragma unroll
        for (int ks = 0; ks < 2; ks++) {
            ah[ks] = *(const s16x8*)&Xh[(16 * wv + lm) * 72 + ks * 32 + quad * 8];
            al[ks] = *(const s16x8*)&Xl[(16 * wv + lm) * 72 + ks * 32 + quad * 8];
        }
        #pragma unroll
        for (int nt = 0; nt < 4; nt++) {
            #pragma unroll
            for (int ks = 0; ks < 2; ks++) {
                s16x8 bh = *(const s16x8*)&Wh[(16 * nt + lm) * 72 + ks * 32 + quad * 8];
                s16x8 bl = *(const s16x8*)&Wl[(16 * nt + lm) * 72 + ks * 32 + quad * 8];
                acc[nt] = MFMA(ah[ks], bh, acc[nt]);
                acc[nt] = MFMA(ah[ks], bl, acc[nt]);
                acc[nt] = MFMA(al[ks], bh, acc[nt]);
            }
        }
    }
    #pragma unroll
    for (int nt = 0; nt < 4; nt++) {
        const int c = c0 + 16 * nt + lm;
        const int s = c >> 9, hd = c & 511, h = hd >> 6, d = hd & 63;
        u32_t* dst = (s == 0) ? q32 : (s == 1) ? k32 : v32;
        #pragma unroll
        for (int r = 0; r < 4; r++) {
            const int m = m0 + 16 * wv + 4 * quad + r;
            const int b = m >> 10, n = m & (Nn - 1);
            dst[(((size_t)b * Hh + h) * Nn + n) * HDd + d] = pack32(acc[nt][r]);
        }
    }
}

// ---------- Kernel B: flash attention (round-4 proven body: 135 us) ----------
// Q frags direct from global (no Q LDS); V staged via (jo,dch) map; mask bit-packed;
// swapped QK^T -> lane-local softmax; P in LDS XOR-swizzled; reg-prefetch pipeline
// with lgkm-only barriers (2 per iter).
__global__ __launch_bounds__(256, 2) void attn_mfma(const u32_t* __restrict__ q32,
                                                    const u32_t* __restrict__ k32,
                                                    const u32_t* __restrict__ v32,
                                                    const float* __restrict__ ef,
                                                    const u32_t* __restrict__ mb,
                                                    const int* __restrict__ anyB,
                                                    const float* __restrict__ wep,
                                                    const float* __restrict__ weg,
                                                    const float* __restrict__ beg,
                                                    u32_t* __restrict__ aoutp) {
    // LDS: K 18432 + VT 22528 + P 17408 = 58368 B
    __shared__ __align__(16) u16_t Kh[64 * 72], Kl[64 * 72];
    __shared__ __align__(16) u16_t VTh[64 * 88], VTl[64 * 88];
    __shared__ __align__(16) u32_t Ppk[64 * 68];

    const int tid = threadIdx.x;
    const int wv = tid >> 6, lane = tid & 63, lm = lane & 15, quad = lane >> 4;
    const int i0 = blockIdx.x * 64;
    const int h  = blockIdx.y;
    const int b  = blockIdx.z;
    const int row = tid >> 2, dq = tid & 3;     // K staging map
    const int jo = tid >> 5, dch = tid & 31;    // V staging map

    const uint4* kg4 = (const uint4*)(k32 + (((size_t)b * Hh + h) * Nn) * HDd);
    const uint2* vg2 = (const uint2*)(v32 + (((size_t)b * Hh + h) * Nn) * HDd);
    const u32_t* mbB = mb + b * 32;

    const int i_sm = i0 + 16 * wv + lm;          // this lane's softmax row

    // ---- prologue: issue Q-frag, K(0), V(0), ef(0), mask(0) loads ----
    const u32_t* qrow = q32 + (((size_t)b * Hh + h) * Nn + i_sm) * HDd;
    uint4 qA0 = *(const uint4*)&qrow[quad * 8];
    uint4 qB0 = *(const uint4*)&qrow[quad * 8 + 4];
    uint4 qA1 = *(const uint4*)&qrow[32 + quad * 8];
    uint4 qB1 = *(const uint4*)&qrow[32 + quad * 8 + 4];
    const size_t kb0 = (size_t)row * 16 + dq * 4;
    uint4 kr0 = kg4[kb0 + 0], kr1 = kg4[kb0 + 1], kr2 = kg4[kb0 + 2], kr3 = kg4[kb0 + 3];
    uint2 vq0 = vg2[(8 * jo + 0) * 32 + dch], vq1 = vg2[(8 * jo + 1) * 32 + dch],
          vq2 = vg2[(8 * jo + 2) * 32 + dch], vq3 = vg2[(8 * jo + 3) * 32 + dch],
          vq4 = vg2[(8 * jo + 4) * 32 + dch], vq5 = vg2[(8 * jo + 5) * 32 + dch],
          vq6 = vg2[(8 * jo + 6) * 32 + dch], vq7 = vg2[(8 * jo + 7) * 32 + dch];

    const float* efL = ef + ((size_t)(b * Nn + i_sm) * Nn + 4 * quad) * Ee;
    uint2 mwc = *(const uint2*)&mbB[0];
    float4 er4[4][5];
    #pragma unroll
    for (int jn = 0; jn < 4; jn++) {
        const float4* p4 = (const float4*)(efL + (size_t)(16 * jn) * Ee);
        #pragma unroll
        for (int c = 0; c < 5; c++) er4[jn][c] = p4[c];
    }

    const float wp0 = wep[h*Ee+0], wp1 = wep[h*Ee+1], wp2 = wep[h*Ee+2],
                wp3 = wep[h*Ee+3], wp4 = wep[h*Ee+4];
    const float wg0 = weg[h*Ee+0], wg1 = weg[h*Ee+1], wg2 = weg[h*Ee+2],
                wg3 = weg[h*Ee+3], wg4 = weg[h*Ee+4];
    const float bgs = beg[h];
    const int anyb = anyB[b];
    const int rvs = anyb && ((mbB[i_sm >> 5] >> (i_sm & 31)) & 1);

    // ---- Q fragments in registers (no LDS round-trip) ----
    s16x8 qh[2], ql[2];
    unpk8(qA0, qB0, qh[0], ql[0]);
    unpk8(qA1, qB1, qh[1], ql[1]);

    float m_ = -1e30f, l_ = 0.f;
    f32x4 accO[4];
    #pragma unroll
    for (int dn = 0; dn < 4; dn++) accO[dn] = {0.f, 0.f, 0.f, 0.f};
    const int xk = 8 * (lm & 3);                 // P column XOR-swizzle key

    for (int jt = 0; jt < Nn / 64; jt++) {
        const int jtn = (jt + 1 < Nn / 64) ? jt + 1 : Nn / 64 - 1;
        const int j0n = jtn * 64;

        lds_barrier();   // A: all waves' prev-tile frag reads done

        // ---- stage K from regs: [j][d] split ----
        stage16(kr0, kr1, kr2, kr3, &Kh[row * 72 + dq * 16], &Kl[row * 72 + dq * 16]);
        // ---- stage V transposed from regs: 2 full hi/lo rows per lane, uint4 writes ----
        {
            const int d0 = 2 * dch, d1 = d0 + 1;
            uint4 H0 = make_uint4(HHW(vq0.x, vq1.x), HHW(vq2.x, vq3.x),
                                  HHW(vq4.x, vq5.x), HHW(vq6.x, vq7.x));
            uint4 L0 = make_uint4(LLW(vq0.x, vq1.x), LLW(vq2.x, vq3.x),
                                  LLW(vq4.x, vq5.x), LLW(vq6.x, vq7.x));
            uint4 H1 = make_uint4(HHW(vq0.y, vq1.y), HHW(vq2.y, vq3.y),
                                  HHW(vq4.y, vq5.y), HHW(vq6.y, vq7.y));
            uint4 L1 = make_uint4(LLW(vq0.y, vq1.y), LLW(vq2.y, vq3.y),
                                  LLW(vq4.y, vq5.y), LLW(vq6.y, vq7.y));
            *(uint4*)&VTh[d0 * 88 + 8 * jo] = H0;
            *(uint4*)&VTl[d0 * 88 + 8 * jo] = L0;
            *(uint4*)&VTh[d1 * 88 + 8 * jo] = H1;
            *(uint4*)&VTl[d1 * 88 + 8 * jo] = L1;
        }
        // ---- issue next-tile K/V loads (in flight across barrier B + compute) ----
        {
            const size_t kbn = (size_t)(j0n + row) * 16 + dq * 4;
            kr0 = kg4[kbn + 0]; kr1 = kg4[kbn + 1]; kr2 = kg4[kbn + 2]; kr3 = kg4[kbn + 3];
            vq0 = vg2[(j0n + 8 * jo + 0) * 32 + dch];
            vq1 = vg2[(j0n + 8 * jo + 1) * 32 + dch];
            vq2 = vg2[(j0n + 8 * jo + 2) * 32 + dch];
            vq3 = vg2[(j0n + 8 * jo + 3) * 32 + dch];
            vq4 = vg2[(j0n + 8 * jo + 4) * 32 + dch];
            vq5 = vg2[(j0n + 8 * jo + 5) * 32 + dch];
            vq6 = vg2[(j0n + 8 * jo + 6) * 32 + dch];
            vq7 = vg2[(j0n + 8 * jo + 7) * 32 + dch];
        }

        lds_barrier();   // B: K/VT visible

        // ---- QK^T swapped: Sp[jn][r] = S[j0+16jn+4quad+r][i0+16wv+lm] ----
        f32x4 Sp[4];
        #pragma unroll
        for (int jn = 0; jn < 4; jn++) {
            f32x4 s = {0.f, 0.f, 0.f, 0.f};
            #pragma unroll
            for (int ks = 0; ks < 2; ks++) {
                s16x8 kh = *(const s16x8*)&Kh[(16 * jn + lm) * 72 + ks * 32 + quad * 8];
                s16x8 kl = *(const s16x8*)&Kl[(16 * jn + lm) * 72 + ks * 32 + quad * 8];
                s = MFMA(kh, qh[ks], s);
                s = MFMA(kh, ql[ks], s);
                s = MFMA(kl, qh[ks], s);
            }
            Sp[jn] = s;
        }

        // ---- gate/bias/mask (consumes er4/mwc of THIS tile) ----
        const u32_t sj0 = mwc.x >> (4 * quad), sj1 = mwc.x >> (4 * quad + 16);
        const u32_t sj2 = mwc.y >> (4 * quad), sj3 = mwc.y >> (4 * quad + 16);
        const u32_t sj[4] = {sj0, sj1, sj2, sj3};
        float pp[4][4];
        #pragma unroll
        for (int jn = 0; jn < 4; jn++) {
            #pragma unroll
            for (int r = 0; r < 4; r++) {
                const int mjv = (sj[jn] >> r) & 1;
                const int f = r * 5;
                const float e0 = er4[jn][(f+0)>>2][(f+0)&3];
                const float e1 = er4[jn][(f+1)>>2][(f+1)&3];
                const float e2 = er4[jn][(f+2)>>2][(f+2)&3];
                const float e3 = er4[jn][(f+3)>>2][(f+3)&3];
                const float e4 = er4[jn][(f+4)>>2][(f+4)&3];
                const float bias = fmaf(e0, wp0, fmaf(e1, wp1, fmaf(e2, wp2, fmaf(e3, wp3, e4 * wp4))));
                const float gv = fmaf(e0, wg0, fmaf(e1, wg1, fmaf(e2, wg2, fmaf(e3, wg3, fmaf(e4, wg4, bgs)))));
                const float gate = __builtin_amdgcn_rcpf(1.f + __expf(-gv));
                const float val = fmaf(Sp[jn][r], 0.125f, gate * bias);
                pp[jn][r] = rvs ? (mjv ? val : -1e30f) : 0.f;
            }
        }
        // ---- reload ef/mask for next tile ----
        mwc = *(const uint2*)&mbB[j0n >> 5];
        #pragma unroll
        for (int jn = 0; jn < 4; jn++) {
            const float4* p4 = (const float4*)(efL + (size_t)(j0n + 16 * jn) * Ee);
            #pragma unroll
            for (int c = 0; c < 5; c++) er4[jn][c] = p4[c];
        }

        // ---- lane-local online softmax ----
        float tmax = fmaxf(fmaxf(fmaxf(pp[0][0], pp[0][1]), fmaxf(pp[0][2], pp[0][3])),
                           fmaxf(fmaxf(pp[1][0], pp[1][1]), fmaxf(pp[1][2], pp[1][3])));
        tmax = fmaxf(tmax,
               fmaxf(fmaxf(fmaxf(pp[2][0], pp[2][1]), fmaxf(pp[2][2], pp[2][3])),
                     fmaxf(fmaxf(pp[3][0], pp[3][1]), fmaxf(pp[3][2], pp[3][3]))));
        tmax = fmaxf(tmax, __shfl_xor(tmax, 16));
        tmax = fmaxf(tmax, __shfl_xor(tmax, 32));
        const float mnew = fmaxf(m_, tmax);
        const float alpha = __expf(m_ - mnew);
        float ps = 0.f;
        #pragma unroll
        for (int jn = 0; jn < 4; jn++)
            #pragma unroll
            for (int r = 0; r < 4; r++) { pp[jn][r] = __expf(pp[jn][r] - mnew); ps += pp[jn][r]; }
        ps += __shfl_xor(ps, 16);
        ps += __shfl_xor(ps, 32);
        m_ = mnew;
        l_ = l_ * alpha + ps;
        float a4[4];
        #pragma unroll
        for (int r = 0; r < 4; r++) a4[r] = __shfl(alpha, 4 * quad + r);
        #pragma unroll
        for (int dn = 0; dn < 4; dn++)
            #pragma unroll
            for (int r = 0; r < 4; r++) accO[dn][r] *= a4[r];

        // ---- P write: own row, XOR-swizzled cols (wave-private rows, no barrier) ----
        #pragma unroll
        for (int jn = 0; jn < 4; jn++) {
            #pragma unroll
            for (int p = 0; p < 2; p++) {
                const int col = (16 * jn + 4 * quad + 2 * p) ^ xk;
                *(uint2*)&Ppk[(16 * wv + lm) * 68 + col] =
                    make_uint2(pack32(pp[jn][2 * p]), pack32(pp[jn][2 * p + 1]));
            }
        }

        // ---- PV ----
        s16x8 ph[2], pl[2];
        #pragma unroll
        for (int ks2 = 0; ks2 < 2; ks2++) {
            const int off = (16 * wv + lm) * 68 + ((ks2 * 32 + quad * 8) ^ xk);
            uint4 A = *(const uint4*)&Ppk[off];
            uint4 B2 = *(const uint4*)&Ppk[off + 4];
            unpk8(A, B2, ph[ks2], pl[ks2]);
        }
        #pragma unroll
        for (int dn = 0; dn < 4; dn++) {
            f32x4 c = accO[dn];
            #pragma unroll
            for (int ks2 = 0; ks2 < 2; ks2++) {
                s16x8 vh = *(const s16x8*)&VTh[(16 * dn + lm) * 88 + ks2 * 32 + quad * 8];
                s16x8 vl = *(const s16x8*)&VTl[(16 * dn + lm) * 88 + ks2 * 32 + quad * 8];
                c = MFMA(ph[ks2], vh, c);
                c = MFMA(ph[ks2], vl, c);
                c = MFMA(pl[ks2], vh, c);
            }
            accO[dn] = c;
        }
    }

    // ---- epilogue: broadcast l, normalize, store packed ----
    float linv[4];
    #pragma unroll
    for (int r = 0; r < 4; r++) linv[r] = __builtin_amdgcn_rcpf(__shfl(l_, 4 * quad + r));
    #pragma unroll
    for (int r = 0; r < 4; r++) {
        const int i = i0 + 16 * wv + 4 * quad + r;
        #pragma unroll
        for (int dn = 0; dn < 4; dn++)
            aoutp[(size_t)(b * Nn + i) * Dd + h * HDd + 16 * dn + lm] = pack32(accO[dn][r] * linv[r]);
    }
}

// ---------- Kernel C: out = aout @ w_proj^T + bias; reg-prefetch + lgkm barriers ----------
__global__ __launch_bounds__(256) void out_mfma(const u32_t* __restrict__ ap,
                                                const u32_t* __restrict__ wp,
                                                const float* __restrict__ bias,
                                                float* __restrict__ out) {
    __shared__ __align__(16) u16_t Xh[64 * 72], Xl[64 * 72];
    __shared__ __align__(16) u16_t Wh[64 * 72], Wl[64 * 72];
    const int tid = threadIdx.x;
    const int wv = tid >> 6, lane = tid & 63, lm = lane & 15, quad = lane >> 4;
    const int m0 = blockIdx.y * 64, c0 = blockIdx.x * 64;
    const int row = tid >> 2, dq = tid & 3;
    const uint4* a4 = (const uint4*)ap;
    const uint4* w4 = (const uint4*)wp;

    const size_t ab0 = (size_t)(m0 + row) * 128 + dq * 4;
    const size_t wb0 = (size_t)(c0 + row) * 128 + dq * 4;
    uint4 xa0 = a4[ab0 + 0], xa1 = a4[ab0 + 1], xa2 = a4[ab0 + 2], xa3 = a4[ab0 + 3];
    uint4 wa0 = w4[wb0 + 0], wa1 = w4[wb0 + 1], wa2 = w4[wb0 + 2], wa3 = w4[wb0 + 3];

    f32x4 acc[4];
    #pragma unroll
    for (int nt = 0; nt < 4; nt++) acc[nt] = {0.f, 0.f, 0.f, 0.f};

    for (int kt = 0; kt < 8; kt++) {
        lds_barrier();
        stage16(xa0, xa1, xa2, xa3, &Xh[row * 72 + dq * 16], &Xl[row * 72 + dq * 16]);
        stage16(wa0, wa1, wa2, wa3, &Wh[row * 72 + dq * 16], &Wl[row * 72 + dq * 16]);
        const int ktn = (kt < 7) ? kt + 1 : 7;
        xa0 = a4[ab0 + ktn * 16 + 0]; xa1 = a4[ab0 + ktn * 16 + 1];
        xa2 = a4[ab0 + ktn * 16 + 2]; xa3 = a4[ab0 + ktn * 16 + 3];
        wa0 = w4[wb0 + ktn * 16 + 0]; wa1 = w4[wb0 + ktn * 16 + 1];
        wa2 = w4[wb0 + ktn * 16 + 2]; wa3 = w4[wb0 + ktn * 16 + 3];
        lds_barrier();
        s16x8 ah[2], al[2];
        #pragma unroll
        for (int ks = 0; ks < 2; ks++) {
            ah[ks] = *(const s16x8*)&Xh[(16 * wv + lm) * 72 + ks * 32 + quad * 8];
            al[ks] = *(const s16x8*)&Xl[(16 * wv + lm) * 72 + ks * 32 + quad * 8];
        }
        #pragma unroll
        for (int nt = 0; nt < 4; nt++) {
            #pragma unroll
            for (int ks = 0; ks < 2; ks++) {
                s16x8 bh = *(const s16x8*)&Wh[(16 * nt + lm) * 72 + ks * 32 + quad * 8];
                s16x8 bl = *(const s16x8*)&Wl[(16 * nt + lm) * 72 + ks * 32 + quad * 8];
                acc[nt] = MFMA(ah[ks], bh, acc[nt]);
                acc[nt] = MFMA(ah[ks], bl, acc[nt]);
                acc[nt] = MFMA(al[ks], bh, acc[nt]);
            }
        }
    }
    #pragma unroll
    for (int nt = 0; nt < 4; nt++) {
        const int c = c0 + 16 * nt + lm;
        const float bc = bias[c];
        #pragma unroll
        for (int r = 0; r < 4; r++) {
            const int m = m0 + 16 * wv + 4 * quad + r;
            out[(size_t)m * Dd + c] = acc[nt][r] + bc;
        }
    }
}

extern "C" void kernel_launch(void* const* d_in, const int* in_sizes, int n_in,
                              void* d_out, int out_size, void* d_ws, size_t ws_size,
                              hipStream_t stream) {
    const float* x    = (const float*)d_in[0];
    const float* ef   = (const float*)d_in[1];
    const void*  msk  = d_in[2];
    const float* wqkv = (const float*)d_in[3];
    const float* wep  = (const float*)d_in[4];
    const float* weg  = (const float*)d_in[5];
    const float* beg  = (const float*)d_in[6];
    const float* wpj  = (const float*)d_in[7];
    const float* bpj  = (const float*)d_in[8];
    float* out = (float*)d_out;

    u32_t* mbits = (u32_t*)d_ws;                  // 128 u32 bit-packed mask
    int* anyB = (int*)(mbits + 128);              // 16 ints
    u32_t* q32 = (u32_t*)(anyB + 16);
    const size_t per = (size_t)Bb * Hh * Nn * HDd;   // 2,097,152
    u32_t* k32 = q32 + per;
    u32_t* v32 = k32 + per;
    u32_t* aop = v32 + per;                       // B*N*D packed u32
    u32_t* xp  = aop + (size_t)Bb * Nn * Dd;      // B*N*D packed u32
    u32_t* wqp = xp + (size_t)Bb * Nn * Dd;       // 3*D*D packed u32
    u32_t* wpp = wqp + (size_t)3 * Dd * Dd;       // D*D packed u32

    pack_prep<<<1025, 256, 0, stream>>>(x, wqkv, wpj, msk, xp, wqp, wpp, mbits, anyB);
    qkv_mfma<<<dim3(24, 32), 512, 0, stream>>>(xp, wqp, q32, k32, v32);
    attn_mfma<<<dim3(Nn / 64, Hh, Bb), 256, 0, stream>>>(q32, k32, v32, ef, mbits, anyB,
                                                         wep, weg, beg, aop);
    out_mfma<<<dim3(8, 64), 256, 0, stream>>>(aop, wpp, bpj, out);
}